// Round 7
// baseline (1683.962 us; speedup 1.0000x reference)
//
#include <hip/hip_runtime.h>

#define NN 100000
#define EE 400000
#define HH 512
#define NB_SCAN 98   // ceil(NN/1024)

typedef __attribute__((ext_vector_type(8))) short short8;
typedef __attribute__((ext_vector_type(8))) unsigned short ushort8;
typedef __attribute__((ext_vector_type(4))) float f32x4;

__device__ inline unsigned short f2b(float f) {   // f32 -> bf16 RNE
    unsigned int u = __float_as_uint(f);
    return (unsigned short)((u + 0x7fffu + ((u >> 16) & 1u)) >> 16);
}
__device__ inline float b2f(unsigned short b) {
    return __uint_as_float(((unsigned int)b) << 16);
}

// ================= CSR build =================
__global__ void histo_deg(const int* __restrict__ dst, int* __restrict__ deg) {
    int e = blockIdx.x * blockDim.x + threadIdx.x;
    if (e < EE) atomicAdd(&deg[dst[e]], 1);
}

__global__ void scan_reduce(const int* __restrict__ deg, int* __restrict__ blockSums) {
    __shared__ int s[256];
    int b = blockIdx.x, t = threadIdx.x;
    int base = b * 1024 + t * 4;
    int v = 0;
    #pragma unroll
    for (int j = 0; j < 4; ++j) { int i = base + j; if (i < NN) v += deg[i]; }
    s[t] = v; __syncthreads();
    for (int off = 128; off > 0; off >>= 1) {
        if (t < off) s[t] += s[t + off];
        __syncthreads();
    }
    if (t == 0) blockSums[b] = s[0];
}

__global__ void scan_top(int* __restrict__ blockSums, int* __restrict__ start) {
    __shared__ int s[128];
    int t = threadIdx.x;
    s[t] = (t < NB_SCAN) ? blockSums[t] : 0;
    __syncthreads();
    for (int off = 1; off < 128; off <<= 1) {
        int u = (t >= off) ? s[t - off] : 0;
        __syncthreads();
        s[t] += u;
        __syncthreads();
    }
    if (t < NB_SCAN) blockSums[t] = (t == 0) ? 0 : s[t - 1];  // exclusive
    if (t == 0) start[NN] = EE;
}

__global__ void scan_down(const int* __restrict__ deg, const int* __restrict__ blockSums,
                          int* __restrict__ start, int* __restrict__ cursor) {
    __shared__ int s[256];
    int b = blockIdx.x, t = threadIdx.x;
    int base = b * 1024 + t * 4;
    int v[4]; int sum = 0;
    #pragma unroll
    for (int j = 0; j < 4; ++j) {
        int i = base + j;
        v[j] = (i < NN) ? deg[i] : 0;
        sum += v[j];
    }
    s[t] = sum; __syncthreads();
    for (int off = 1; off < 256; off <<= 1) {
        int u = (t >= off) ? s[t - off] : 0;
        __syncthreads();
        s[t] += u;
        __syncthreads();
    }
    int excl = blockSums[b] + ((t == 0) ? 0 : s[t - 1]);
    #pragma unroll
    for (int j = 0; j < 4; ++j) {
        int i = base + j;
        if (i < NN) { start[i] = excl; cursor[i] = excl; excl += v[j]; }
    }
}

__global__ void csr_fill(const int* __restrict__ src, const int* __restrict__ dst,
                         int* __restrict__ cursor, int* __restrict__ eidx) {
    int e = blockIdx.x * blockDim.x + threadIdx.x;
    if (e < EE) {
        int p = atomicAdd(&cursor[dst[e]], 1);
        eidx[p] = src[e];
    }
}

// ================= Weight transpose + bf16 convert =================
__global__ void w_transpose(const float* __restrict__ w, unsigned short* __restrict__ wt) {
    int idx = blockIdx.x * 256 + threadIdx.x;  // n*512 + k, k fastest
    int n = idx >> 9, k = idx & 511;
    wt[idx] = f2b(w[(size_t)k * HH + n]);
}

// ================= Aggregation: bf16 gather, one wave per node =================
__global__ __launch_bounds__(256) void gather_rows_b(
    const unsigned short* __restrict__ xb, const int* __restrict__ start,
    const int* __restrict__ eidx, unsigned short* __restrict__ agg)
{
    int node = blockIdx.x * 4 + (threadIdx.x >> 6);
    if (node >= NN) return;
    int c0 = (threadIdx.x & 63) << 3;   // 8 bf16 per lane
    float a[8] = {0.f,0.f,0.f,0.f,0.f,0.f,0.f,0.f};
    int e1 = start[node + 1];
    for (int e = start[node]; e < e1; ++e) {
        ushort8 v = *(const ushort8*)(xb + (size_t)eidx[e] * HH + c0);
        #pragma unroll
        for (int j = 0; j < 8; ++j) a[j] += b2f(v[j]);
    }
    ushort8 o;
    #pragma unroll
    for (int j = 0; j < 8; ++j) o[j] = f2b(a[j]);
    *(ushort8*)(agg + (size_t)node * HH + c0) = o;
}

// Layer-1 scalar aggregate via CSR
__global__ void gather_scalar(const float* __restrict__ x, const int* __restrict__ start,
                              const int* __restrict__ eidx, float* __restrict__ agg0) {
    int i = blockIdx.x * blockDim.x + threadIdx.x;
    if (i >= NN) return;
    float s = 0.f;
    int e1 = start[i + 1];
    for (int e = start[i]; e < e1; ++e) s += x[eidx[e]];
    agg0[i] = s;
}

// x1[i][h] = relu(agg0[i]*w_rel[h] + b[h] + x[i]*w_root[h]); writes f32 + bf16
__global__ void layer1_expand(const float* __restrict__ x,
                              const float* __restrict__ agg0,
                              const float* __restrict__ w_rel,
                              const float* __restrict__ b,
                              const float* __restrict__ w_root,
                              float* __restrict__ x1,
                              unsigned short* __restrict__ x1b) {
    int idx = blockIdx.x * blockDim.x + threadIdx.x;
    int i = idx >> 7;
    if (i >= NN) return;
    int q = (idx & 127) << 2;
    float a = agg0[i], xv = x[i];
    float4 wr = *(const float4*)&w_rel[q];
    float4 bb = *(const float4*)&b[q];
    float4 wt = *(const float4*)&w_root[q];
    float4 o;
    o.x = fmaxf(fmaf(a, wr.x, fmaf(xv, wt.x, bb.x)), 0.f);
    o.y = fmaxf(fmaf(a, wr.y, fmaf(xv, wt.y, bb.y)), 0.f);
    o.z = fmaxf(fmaf(a, wr.z, fmaf(xv, wt.z, bb.z)), 0.f);
    o.w = fmaxf(fmaf(a, wr.w, fmaf(xv, wt.w, bb.w)), 0.f);
    *(float4*)&x1[(size_t)i * HH + q] = o;
    ushort4 ob = { f2b(o.x), f2b(o.y), f2b(o.z), f2b(o.w) };
    *(ushort4*)&x1b[(size_t)i * HH + q] = ob;
}

// ================= MFMA GEMM — barrier-free, register-direct =================
// out = (relu?)(AB@WrT^T + XBp@WoT^T + bias) + resid
// No LDS, no barriers. Each lane loads its MFMA fragments straight from
// global (L2) into VGPRs; 4 rotating register sets give 3 compute-phases of
// prefetch lead. Compiler emits counted vmcnt for pure reg loads.
// Wave tile 64x64, block tile 128x128 (4 waves, 2x2), BK=32, K=1024 combined.

#define LOADF(S, T) {                                                          \
    const unsigned short* Ab_ = ((T) < 16) ? AB : XBp;                         \
    const unsigned short* Wb_ = ((T) < 16) ? WrT : WoT;                        \
    const unsigned kk_ = ((unsigned)(T) & 15u) << 5;                           \
    _Pragma("unroll")                                                          \
    for (int m_ = 0; m_ < 4; ++m_)                                             \
        af[S][m_] = *(const short8*)(Ab_ + offA[m_] + kk_);                    \
    _Pragma("unroll")                                                          \
    for (int n_ = 0; n_ < 4; ++n_)                                             \
        bf[S][n_] = *(const short8*)(Wb_ + offB[n_] + kk_); }

#define COMPF(S) {                                                             \
    _Pragma("unroll")                                                          \
    for (int m_ = 0; m_ < 4; ++m_)                                             \
        _Pragma("unroll")                                                      \
        for (int n_ = 0; n_ < 4; ++n_)                                         \
            acc[m_][n_] = __builtin_amdgcn_mfma_f32_16x16x32_bf16(             \
                af[S][m_], bf[S][n_], acc[m_][n_], 0, 0, 0); }

template<bool RELU, bool RB16, bool WF32, bool WB16>
__global__ __launch_bounds__(256, 2) void gemm_mfma(
    const unsigned short* __restrict__ AB, const unsigned short* __restrict__ XBp,
    const unsigned short* __restrict__ WrT, const unsigned short* __restrict__ WoT,
    const float* __restrict__ bias, const void* __restrict__ residv,
    float* __restrict__ out, unsigned short* __restrict__ outb)
{
    const int tid  = threadIdx.x;
    const int wave = tid >> 6, lane = tid & 63;

    // Bijective XCD-chunked mapping: 3128 blocks = 8 XCDs x 391.
    const int bid = blockIdx.x;
    const int nid = (bid & 7) * 391 + (bid >> 3);
    const int col0 = (nid & 3) << 7;   // n-tile fastest within chunk -> A-panel L2 reuse
    const int row0 = (nid >> 2) << 7;

    const int wr = wave >> 1, wc = wave & 1; // wave's 64x64 quadrant
    const int l16 = lane & 15, lq = lane >> 4;

    // Per-lane fragment offsets (ushort units); kk added per K-step.
    unsigned offA[4], offB[4];
    #pragma unroll
    for (int m = 0; m < 4; ++m) {
        int r = row0 + wr * 64 + m * 16 + l16;
        if (r >= NN) r = NN - 1;            // clamp: valid reads, stores guarded
        offA[m] = (unsigned)r * HH + lq * 8;
    }
    #pragma unroll
    for (int n = 0; n < 4; ++n) {
        int c = col0 + wc * 64 + n * 16 + l16;
        offB[n] = (unsigned)c * HH + lq * 8;
    }

    f32x4 acc[4][4];
    #pragma unroll
    for (int m = 0; m < 4; ++m)
        #pragma unroll
        for (int n = 0; n < 4; ++n)
            acc[m][n] = (f32x4){0.f, 0.f, 0.f, 0.f};

    short8 af[4][4], bf[4][4];   // [set][frag] — sets indexed by literals only

    // Prologue: fill all 4 sets (32 loads in flight).
    LOADF(0, 0) LOADF(1, 1) LOADF(2, 2) LOADF(3, 3)

    // Steady state: compute set S, immediately refill it for t+4.
    #pragma unroll 1
    for (int tb = 0; tb < 28; tb += 4) {
        COMPF(0) LOADF(0, tb + 4)
        COMPF(1) LOADF(1, tb + 5)
        COMPF(2) LOADF(2, tb + 6)
        COMPF(3) LOADF(3, tb + 7)
    }
    // Tail: last 4 K-steps, no more loads.
    COMPF(0) COMPF(1) COMPF(2) COMPF(3)

    // Epilogue: + bias (+relu) + resid; optional f32 / bf16 stores
    const float*          residf = (const float*)residv;
    const unsigned short* residb = (const unsigned short*)residv;
    float bias_n[4];
    #pragma unroll
    for (int n = 0; n < 4; ++n) bias_n[n] = bias[col0 + wc * 64 + n * 16 + l16];

    #pragma unroll
    for (int m = 0; m < 4; ++m) {
        #pragma unroll
        for (int j = 0; j < 4; ++j) {
            int row = row0 + wr * 64 + m * 16 + lq * 4 + j;
            if (row >= NN) continue;
            #pragma unroll
            for (int n = 0; n < 4; ++n) {
                int col = col0 + wc * 64 + n * 16 + l16;
                size_t off = (size_t)row * HH + col;
                float v = acc[m][n][j] + bias_n[n];
                if (RELU) v = fmaxf(v, 0.f);
                v += RB16 ? b2f(residb[off]) : residf[off];
                if (WF32) out[off] = v;
                if (WB16) outb[off] = f2b(v);
            }
        }
    }
}

extern "C" void kernel_launch(void* const* d_in, const int* in_sizes, int n_in,
                              void* d_out, int out_size, void* d_ws, size_t ws_size,
                              hipStream_t stream) {
    const float* x   = (const float*)d_in[0];
    const int*   ei  = (const int*)d_in[1];
    const int*   src = ei;
    const int*   dst = ei + EE;
    const float* w_rel1  = (const float*)d_in[2];
    const float* b_rel1  = (const float*)d_in[3];
    const float* w_root1 = (const float*)d_in[4];
    const float* w_rel2  = (const float*)d_in[5];
    const float* b_rel2  = (const float*)d_in[6];
    const float* w_root2 = (const float*)d_in[7];
    const float* w_rel3  = (const float*)d_in[8];
    const float* b_rel3  = (const float*)d_in[9];
    const float* w_root3 = (const float*)d_in[10];
    const float* w_rel4  = (const float*)d_in[11];
    const float* b_rel4  = (const float*)d_in[12];
    const float* w_root4 = (const float*)d_in[13];

    const size_t NH = (size_t)NN * HH;
    float*          W0   = (float*)d_ws;                 // x1 (f32), then x3 (f32)
    unsigned short* XB   = (unsigned short*)(W0 + NH);   // bf16 ping (x1, then x3)
    unsigned short* XB2  = XB + NH;                      // bf16 pong (x2)
    unsigned short* AGB  = XB2 + NH;                     // agg bf16
    unsigned short* WT   = AGB + NH;                     // 6 transposed bf16 weights
    float*          agg0 = (float*)(WT + 6 * 262144);
    int*            csr  = (int*)(agg0 + NN);
    int* deg       = csr;
    int* start     = csr + NN;
    int* cursor    = start + NN + 1;
    int* eidx      = cursor + NN;
    int* blockSums = eidx + EE;
    float* out = (float*)d_out;

    unsigned short* WrT2 = WT;
    unsigned short* WoT2 = WT + 1 * 262144;
    unsigned short* WrT3 = WT + 2 * 262144;
    unsigned short* WoT3 = WT + 3 * 262144;
    unsigned short* WrT4 = WT + 4 * 262144;
    unsigned short* WoT4 = WT + 5 * 262144;

    const int gGemm = 3128;  // 782 m-tiles x 4 n-tiles, XCD-chunked in-kernel

    // ---- CSR build ----
    hipMemsetAsync(deg, 0, NN * sizeof(int), stream);
    histo_deg<<<(EE + 255) / 256, 256, 0, stream>>>(dst, deg);
    scan_reduce<<<NB_SCAN, 256, 0, stream>>>(deg, blockSums);
    scan_top<<<1, 128, 0, stream>>>(blockSums, start);
    scan_down<<<NB_SCAN, 256, 0, stream>>>(deg, blockSums, start, cursor);
    csr_fill<<<(EE + 255) / 256, 256, 0, stream>>>(src, dst, cursor, eidx);

    // ---- Weights -> transposed bf16 ----
    w_transpose<<<1024, 256, 0, stream>>>(w_rel2,  WrT2);
    w_transpose<<<1024, 256, 0, stream>>>(w_root2, WoT2);
    w_transpose<<<1024, 256, 0, stream>>>(w_rel3,  WrT3);
    w_transpose<<<1024, 256, 0, stream>>>(w_root3, WoT3);
    w_transpose<<<1024, 256, 0, stream>>>(w_rel4,  WrT4);
    w_transpose<<<1024, 256, 0, stream>>>(w_root4, WoT4);

    // ---- Layer 1: x1 -> W0 (f32) + XB (bf16) ----
    gather_scalar<<<(NN + 255) / 256, 256, 0, stream>>>(x, start, eidx, agg0);
    layer1_expand<<<50000, 256, 0, stream>>>(x, agg0, w_rel1, b_rel1, w_root1, W0, XB);

    // ---- Layer 2: x2 = relu(conv(x1)) + x1 -> XB2 (bf16 only) ----
    gather_rows_b<<<25000, 256, 0, stream>>>(XB, start, eidx, AGB);
    gemm_mfma<true, false, false, true><<<gGemm, 256, 0, stream>>>(
        AGB, XB, WrT2, WoT2, b_rel2, W0, nullptr, XB2);

    // ---- Layer 3: x3 = conv(x2) + x2 -> W0 (f32) + XB (bf16); resid = bf16 x2 ----
    gather_rows_b<<<25000, 256, 0, stream>>>(XB2, start, eidx, AGB);
    gemm_mfma<false, true, true, true><<<gGemm, 256, 0, stream>>>(
        AGB, XB2, WrT3, WoT3, b_rel3, XB2, W0, XB);

    // ---- Layer 4: x4 = conv(x3) + x3 -> d_out (f32); resid = f32 x3 ----
    gather_rows_b<<<25000, 256, 0, stream>>>(XB, start, eidx, AGB);
    gemm_mfma<false, false, true, false><<<gGemm, 256, 0, stream>>>(
        AGB, XB, WrT4, WoT4, b_rel4, W0, out, nullptr);
}

// Round 8
// 1161.624 us; speedup vs baseline: 1.4497x; 1.4497x over previous
//
#include <hip/hip_runtime.h>

#define NN 100000
#define EE 400000
#define HH 512
#define NB_SCAN 98   // ceil(NN/1024)

typedef __attribute__((ext_vector_type(8))) short short8;
typedef __attribute__((ext_vector_type(8))) unsigned short ushort8;
typedef __attribute__((ext_vector_type(4))) float f32x4;

__device__ inline unsigned short f2b(float f) {   // f32 -> bf16 RNE
    unsigned int u = __float_as_uint(f);
    return (unsigned short)((u + 0x7fffu + ((u >> 16) & 1u)) >> 16);
}
__device__ inline float b2f(unsigned short b) {
    return __uint_as_float(((unsigned int)b) << 16);
}

// ================= CSR build =================
__global__ void histo_deg(const int* __restrict__ dst, int* __restrict__ deg) {
    int e = blockIdx.x * blockDim.x + threadIdx.x;
    if (e < EE) atomicAdd(&deg[dst[e]], 1);
}

__global__ void scan_reduce(const int* __restrict__ deg, int* __restrict__ blockSums) {
    __shared__ int s[256];
    int b = blockIdx.x, t = threadIdx.x;
    int base = b * 1024 + t * 4;
    int v = 0;
    #pragma unroll
    for (int j = 0; j < 4; ++j) { int i = base + j; if (i < NN) v += deg[i]; }
    s[t] = v; __syncthreads();
    for (int off = 128; off > 0; off >>= 1) {
        if (t < off) s[t] += s[t + off];
        __syncthreads();
    }
    if (t == 0) blockSums[b] = s[0];
}

__global__ void scan_top(int* __restrict__ blockSums, int* __restrict__ start) {
    __shared__ int s[128];
    int t = threadIdx.x;
    s[t] = (t < NB_SCAN) ? blockSums[t] : 0;
    __syncthreads();
    for (int off = 1; off < 128; off <<= 1) {
        int u = (t >= off) ? s[t - off] : 0;
        __syncthreads();
        s[t] += u;
        __syncthreads();
    }
    if (t < NB_SCAN) blockSums[t] = (t == 0) ? 0 : s[t - 1];  // exclusive
    if (t == 0) start[NN] = EE;
}

__global__ void scan_down(const int* __restrict__ deg, const int* __restrict__ blockSums,
                          int* __restrict__ start, int* __restrict__ cursor) {
    __shared__ int s[256];
    int b = blockIdx.x, t = threadIdx.x;
    int base = b * 1024 + t * 4;
    int v[4]; int sum = 0;
    #pragma unroll
    for (int j = 0; j < 4; ++j) {
        int i = base + j;
        v[j] = (i < NN) ? deg[i] : 0;
        sum += v[j];
    }
    s[t] = sum; __syncthreads();
    for (int off = 1; off < 256; off <<= 1) {
        int u = (t >= off) ? s[t - off] : 0;
        __syncthreads();
        s[t] += u;
        __syncthreads();
    }
    int excl = blockSums[b] + ((t == 0) ? 0 : s[t - 1]);
    #pragma unroll
    for (int j = 0; j < 4; ++j) {
        int i = base + j;
        if (i < NN) { start[i] = excl; cursor[i] = excl; excl += v[j]; }
    }
}

__global__ void csr_fill(const int* __restrict__ src, const int* __restrict__ dst,
                         int* __restrict__ cursor, int* __restrict__ eidx) {
    int e = blockIdx.x * blockDim.x + threadIdx.x;
    if (e < EE) {
        int p = atomicAdd(&cursor[dst[e]], 1);
        eidx[p] = src[e];
    }
}

// ================= Weight transpose + bf16 convert =================
__global__ void w_transpose(const float* __restrict__ w, unsigned short* __restrict__ wt) {
    int idx = blockIdx.x * 256 + threadIdx.x;  // n*512 + k, k fastest
    int n = idx >> 9, k = idx & 511;
    wt[idx] = f2b(w[(size_t)k * HH + n]);
}

// ================= Aggregation: bf16 gather, one wave per node =================
__global__ __launch_bounds__(256) void gather_rows_b(
    const unsigned short* __restrict__ xb, const int* __restrict__ start,
    const int* __restrict__ eidx, unsigned short* __restrict__ agg)
{
    int node = blockIdx.x * 4 + (threadIdx.x >> 6);
    if (node >= NN) return;
    int c0 = (threadIdx.x & 63) << 3;   // 8 bf16 per lane
    float a[8] = {0.f,0.f,0.f,0.f,0.f,0.f,0.f,0.f};
    int e1 = start[node + 1];
    for (int e = start[node]; e < e1; ++e) {
        ushort8 v = *(const ushort8*)(xb + (size_t)eidx[e] * HH + c0);
        #pragma unroll
        for (int j = 0; j < 8; ++j) a[j] += b2f(v[j]);
    }
    ushort8 o;
    #pragma unroll
    for (int j = 0; j < 8; ++j) o[j] = f2b(a[j]);
    *(ushort8*)(agg + (size_t)node * HH + c0) = o;
}

// Layer-1 scalar aggregate via CSR
__global__ void gather_scalar(const float* __restrict__ x, const int* __restrict__ start,
                              const int* __restrict__ eidx, float* __restrict__ agg0) {
    int i = blockIdx.x * blockDim.x + threadIdx.x;
    if (i >= NN) return;
    float s = 0.f;
    int e1 = start[i + 1];
    for (int e = start[i]; e < e1; ++e) s += x[eidx[e]];
    agg0[i] = s;
}

// x1[i][h] = relu(agg0[i]*w_rel[h] + b[h] + x[i]*w_root[h]); writes f32 + bf16
__global__ void layer1_expand(const float* __restrict__ x,
                              const float* __restrict__ agg0,
                              const float* __restrict__ w_rel,
                              const float* __restrict__ b,
                              const float* __restrict__ w_root,
                              float* __restrict__ x1,
                              unsigned short* __restrict__ x1b) {
    int idx = blockIdx.x * blockDim.x + threadIdx.x;
    int i = idx >> 7;
    if (i >= NN) return;
    int q = (idx & 127) << 2;
    float a = agg0[i], xv = x[i];
    float4 wr = *(const float4*)&w_rel[q];
    float4 bb = *(const float4*)&b[q];
    float4 wt = *(const float4*)&w_root[q];
    float4 o;
    o.x = fmaxf(fmaf(a, wr.x, fmaf(xv, wt.x, bb.x)), 0.f);
    o.y = fmaxf(fmaf(a, wr.y, fmaf(xv, wt.y, bb.y)), 0.f);
    o.z = fmaxf(fmaf(a, wr.z, fmaf(xv, wt.z, bb.z)), 0.f);
    o.w = fmaxf(fmaf(a, wr.w, fmaf(xv, wt.w, bb.w)), 0.f);
    *(float4*)&x1[(size_t)i * HH + q] = o;
    ushort4 ob = { f2b(o.x), f2b(o.y), f2b(o.z), f2b(o.w) };
    *(ushort4*)&x1b[(size_t)i * HH + q] = ob;
}

// ================= MFMA GEMM =================
// out = (relu?)(AB@WrT^T + XBp@WoT^T + bias) + resid
// 256x256 tile, 8 waves (2x4, wave tile 128x64), BK=32, 512 threads.
// Double-buffered LDS (R5-proven schedule: stage next buf before compute,
// one barrier per K-step). LDS k-slots XOR-swizzled both sides
// (slot ^= (row>>1)&3; verified conflict-free R4-R6).
__device__ inline void gload16(const void* g, void* l) {
    __builtin_amdgcn_global_load_lds(
        (const __attribute__((address_space(1))) unsigned int*)g,
        (__attribute__((address_space(3))) unsigned int*)l,
        16, 0, 0);
}

template<bool RELU, bool RB16, bool WF32, bool WB16>
__global__ __launch_bounds__(512, 1) void gemm_mfma(
    const unsigned short* __restrict__ AB, const unsigned short* __restrict__ XBp,
    const unsigned short* __restrict__ WrT, const unsigned short* __restrict__ WoT,
    const float* __restrict__ bias, const void* __restrict__ residv,
    float* __restrict__ out, unsigned short* __restrict__ outb)
{
    __shared__ unsigned short As[2 * 256 * 32];  // [buf][row][k], swizzled k-slots
    __shared__ unsigned short Bs[2 * 256 * 32];  // [buf][col][k]
    const int tid  = threadIdx.x;
    const int wave = tid >> 6, lane = tid & 63;

    // Bijective XCD-chunked mapping (m204): 782 blocks, q=97, r=6.
    const int bid  = blockIdx.x;
    const int xcd  = bid & 7;
    const int base = (xcd < 6) ? xcd * 98 : (6 * 98 + (xcd - 6) * 97);
    const int nid  = base + (bid >> 3);
    const int col0 = (nid & 1) << 8;   // 2 n-tiles, n-fastest -> A-panel L2 reuse
    const int row0 = (nid >> 1) << 8;

    const int wr = wave >> 2, wc = wave & 3;   // wave tile: rows wr*128, cols wc*64
    const int l16 = lane & 15, lq = lane >> 4;
    const int sRow = lane >> 2;                                  // staging row in 16-row chunk
    const int sColSwz = (((lane & 3) ^ ((lane >> 3) & 3)) << 3); // swizzled src k-slot (shorts)
    const int xorslot = ((lq ^ ((lane >> 1) & 3)) << 3);         // read-side slot (shorts)

    // Staged global rows/cols (clamped; stores guarded)
    int rowA[2], colB[2];
    #pragma unroll
    for (int i = 0; i < 2; ++i) {
        int chunk = (wave << 1) + i;           // 0..15 -> 256 rows
        int gr = row0 + chunk * 16 + sRow;
        rowA[i] = (gr >= NN) ? (NN - 1) : gr;
        colB[i] = col0 + chunk * 16 + sRow;
    }

    f32x4 acc[8][4];
    #pragma unroll
    for (int m = 0; m < 8; ++m)
        #pragma unroll
        for (int n = 0; n < 4; ++n)
            acc[m][n] = (f32x4){0.f, 0.f, 0.f, 0.f};

    auto STAGE = [&](unsigned short* Asb, unsigned short* Bsb, int t) {
        const int k0 = t << 5;
        const unsigned short* Ap = (k0 < 512) ? AB  : XBp;
        const unsigned short* Wp = (k0 < 512) ? WrT : WoT;
        const int kk = k0 & 511;
        #pragma unroll
        for (int i = 0; i < 2; ++i) {
            int chunk = (wave << 1) + i;
            gload16(Ap + (size_t)rowA[i] * HH + kk + sColSwz, Asb + chunk * 512);
            gload16(Wp + (size_t)colB[i] * HH + kk + sColSwz, Bsb + chunk * 512);
        }
    };

    auto COMPUTE = [&](const unsigned short* Asb, const unsigned short* Bsb) {
        short8 af[8], bfv[4];
        #pragma unroll
        for (int m = 0; m < 8; ++m)
            af[m] = *(const short8*)(Asb + (wr * 128 + m * 16 + l16) * 32 + xorslot);
        #pragma unroll
        for (int n = 0; n < 4; ++n)
            bfv[n] = *(const short8*)(Bsb + (wc * 64 + n * 16 + l16) * 32 + xorslot);
        #pragma unroll
        for (int m = 0; m < 8; ++m)
            #pragma unroll
            for (int n = 0; n < 4; ++n)
                acc[m][n] = __builtin_amdgcn_mfma_f32_16x16x32_bf16(af[m], bfv[n], acc[m][n], 0, 0, 0);
    };

    unsigned short* A0 = As;        unsigned short* A1 = As + 8192;
    unsigned short* B0 = Bs;        unsigned short* B1 = Bs + 8192;

    STAGE(A0, B0, 0);
    __syncthreads();                       // drains vmcnt(0): tile 0 resident
    #pragma unroll 1
    for (int t = 0; t < 32; t += 2) {
        STAGE(A1, B1, t + 1);              // prefetch next tile (hidden under compute)
        COMPUTE(A0, B0);
        __syncthreads();                   // next staged + everyone done with buf0
        if (t + 2 < 32) STAGE(A0, B0, t + 2);
        COMPUTE(A1, B1);
        __syncthreads();
    }

    // Epilogue: + bias (+relu) + resid; optional f32 / bf16 stores
    const float*          residf = (const float*)residv;
    const unsigned short* residb = (const unsigned short*)residv;
    float bias_n[4];
    #pragma unroll
    for (int n = 0; n < 4; ++n) bias_n[n] = bias[col0 + wc * 64 + n * 16 + l16];

    #pragma unroll
    for (int m = 0; m < 8; ++m) {
        #pragma unroll
        for (int j = 0; j < 4; ++j) {
            int row = row0 + wr * 128 + m * 16 + lq * 4 + j;
            if (row >= NN) continue;
            #pragma unroll
            for (int n = 0; n < 4; ++n) {
                int col = col0 + wc * 64 + n * 16 + l16;
                size_t off = (size_t)row * HH + col;
                float v = acc[m][n][j] + bias_n[n];
                if (RELU) v = fmaxf(v, 0.f);
                v += RB16 ? b2f(residb[off]) : residf[off];
                if (WF32) out[off] = v;
                if (WB16) outb[off] = f2b(v);
            }
        }
    }
}

extern "C" void kernel_launch(void* const* d_in, const int* in_sizes, int n_in,
                              void* d_out, int out_size, void* d_ws, size_t ws_size,
                              hipStream_t stream) {
    const float* x   = (const float*)d_in[0];
    const int*   ei  = (const int*)d_in[1];
    const int*   src = ei;
    const int*   dst = ei + EE;
    const float* w_rel1  = (const float*)d_in[2];
    const float* b_rel1  = (const float*)d_in[3];
    const float* w_root1 = (const float*)d_in[4];
    const float* w_rel2  = (const float*)d_in[5];
    const float* b_rel2  = (const float*)d_in[6];
    const float* w_root2 = (const float*)d_in[7];
    const float* w_rel3  = (const float*)d_in[8];
    const float* b_rel3  = (const float*)d_in[9];
    const float* w_root3 = (const float*)d_in[10];
    const float* w_rel4  = (const float*)d_in[11];
    const float* b_rel4  = (const float*)d_in[12];
    const float* w_root4 = (const float*)d_in[13];

    const size_t NH = (size_t)NN * HH;
    float*          W0   = (float*)d_ws;                 // x1 (f32), then x3 (f32)
    unsigned short* XB   = (unsigned short*)(W0 + NH);   // bf16 ping (x1, then x3)
    unsigned short* XB2  = XB + NH;                      // bf16 pong (x2)
    unsigned short* AGB  = XB2 + NH;                     // agg bf16
    unsigned short* WT   = AGB + NH;                     // 6 transposed bf16 weights
    float*          agg0 = (float*)(WT + 6 * 262144);
    int*            csr  = (int*)(agg0 + NN);
    int* deg       = csr;
    int* start     = csr + NN;
    int* cursor    = start + NN + 1;
    int* eidx      = cursor + NN;
    int* blockSums = eidx + EE;
    float* out = (float*)d_out;

    unsigned short* WrT2 = WT;
    unsigned short* WoT2 = WT + 1 * 262144;
    unsigned short* WrT3 = WT + 2 * 262144;
    unsigned short* WoT3 = WT + 3 * 262144;
    unsigned short* WrT4 = WT + 4 * 262144;
    unsigned short* WoT4 = WT + 5 * 262144;

    const int gGemm = 782;   // 391 m-tiles x 2 n-tiles (256x256), XCD-chunked in-kernel

    // ---- CSR build ----
    hipMemsetAsync(deg, 0, NN * sizeof(int), stream);
    histo_deg<<<(EE + 255) / 256, 256, 0, stream>>>(dst, deg);
    scan_reduce<<<NB_SCAN, 256, 0, stream>>>(deg, blockSums);
    scan_top<<<1, 128, 0, stream>>>(blockSums, start);
    scan_down<<<NB_SCAN, 256, 0, stream>>>(deg, blockSums, start, cursor);
    csr_fill<<<(EE + 255) / 256, 256, 0, stream>>>(src, dst, cursor, eidx);

    // ---- Weights -> transposed bf16 ----
    w_transpose<<<1024, 256, 0, stream>>>(w_rel2,  WrT2);
    w_transpose<<<1024, 256, 0, stream>>>(w_root2, WoT2);
    w_transpose<<<1024, 256, 0, stream>>>(w_rel3,  WrT3);
    w_transpose<<<1024, 256, 0, stream>>>(w_root3, WoT3);
    w_transpose<<<1024, 256, 0, stream>>>(w_rel4,  WrT4);
    w_transpose<<<1024, 256, 0, stream>>>(w_root4, WoT4);

    // ---- Layer 1: x1 -> W0 (f32) + XB (bf16) ----
    gather_scalar<<<(NN + 255) / 256, 256, 0, stream>>>(x, start, eidx, agg0);
    layer1_expand<<<50000, 256, 0, stream>>>(x, agg0, w_rel1, b_rel1, w_root1, W0, XB);

    // ---- Layer 2: x2 = relu(conv(x1)) + x1 -> XB2 (bf16 only) ----
    gather_rows_b<<<25000, 256, 0, stream>>>(XB, start, eidx, AGB);
    gemm_mfma<true, false, false, true><<<gGemm, 512, 0, stream>>>(
        AGB, XB, WrT2, WoT2, b_rel2, W0, nullptr, XB2);

    // ---- Layer 3: x3 = conv(x2) + x2 -> W0 (f32) + XB (bf16); resid = bf16 x2 ----
    gather_rows_b<<<25000, 256, 0, stream>>>(XB2, start, eidx, AGB);
    gemm_mfma<false, true, true, true><<<gGemm, 512, 0, stream>>>(
        AGB, XB2, WrT3, WoT3, b_rel3, XB2, W0, XB);

    // ---- Layer 4: x4 = conv(x3) + x3 -> d_out (f32); resid = f32 x3 ----
    gather_rows_b<<<25000, 256, 0, stream>>>(XB, start, eidx, AGB);
    gemm_mfma<false, false, true, false><<<gGemm, 512, 0, stream>>>(
        AGB, XB, WrT4, WoT4, b_rel4, W0, out, nullptr);
}

// Round 9
// 1041.971 us; speedup vs baseline: 1.6161x; 1.1148x over previous
//
#include <hip/hip_runtime.h>

#define NN 100000
#define EE 400000
#define HH 512
#define NB_SCAN 98   // ceil(NN/1024)

typedef __attribute__((ext_vector_type(8))) short short8;
typedef __attribute__((ext_vector_type(8))) unsigned short ushort8;
typedef __attribute__((ext_vector_type(4))) float f32x4;

__device__ inline unsigned short f2b(float f) {   // f32 -> bf16 RNE
    unsigned int u = __float_as_uint(f);
    return (unsigned short)((u + 0x7fffu + ((u >> 16) & 1u)) >> 16);
}
__device__ inline float b2f(unsigned short b) {
    return __uint_as_float(((unsigned int)b) << 16);
}

// ================= CSR build =================
__global__ void histo_deg(const int* __restrict__ dst, int* __restrict__ deg) {
    int e = blockIdx.x * blockDim.x + threadIdx.x;
    if (e < EE) atomicAdd(&deg[dst[e]], 1);
}

__global__ void scan_reduce(const int* __restrict__ deg, int* __restrict__ blockSums) {
    __shared__ int s[256];
    int b = blockIdx.x, t = threadIdx.x;
    int base = b * 1024 + t * 4;
    int v = 0;
    #pragma unroll
    for (int j = 0; j < 4; ++j) { int i = base + j; if (i < NN) v += deg[i]; }
    s[t] = v; __syncthreads();
    for (int off = 128; off > 0; off >>= 1) {
        if (t < off) s[t] += s[t + off];
        __syncthreads();
    }
    if (t == 0) blockSums[b] = s[0];
}

__global__ void scan_top(int* __restrict__ blockSums, int* __restrict__ start) {
    __shared__ int s[128];
    int t = threadIdx.x;
    s[t] = (t < NB_SCAN) ? blockSums[t] : 0;
    __syncthreads();
    for (int off = 1; off < 128; off <<= 1) {
        int u = (t >= off) ? s[t - off] : 0;
        __syncthreads();
        s[t] += u;
        __syncthreads();
    }
    if (t < NB_SCAN) blockSums[t] = (t == 0) ? 0 : s[t - 1];  // exclusive
    if (t == 0) start[NN] = EE;
}

__global__ void scan_down(const int* __restrict__ deg, const int* __restrict__ blockSums,
                          int* __restrict__ start, int* __restrict__ cursor) {
    __shared__ int s[256];
    int b = blockIdx.x, t = threadIdx.x;
    int base = b * 1024 + t * 4;
    int v[4]; int sum = 0;
    #pragma unroll
    for (int j = 0; j < 4; ++j) {
        int i = base + j;
        v[j] = (i < NN) ? deg[i] : 0;
        sum += v[j];
    }
    s[t] = sum; __syncthreads();
    for (int off = 1; off < 256; off <<= 1) {
        int u = (t >= off) ? s[t - off] : 0;
        __syncthreads();
        s[t] += u;
        __syncthreads();
    }
    int excl = blockSums[b] + ((t == 0) ? 0 : s[t - 1]);
    #pragma unroll
    for (int j = 0; j < 4; ++j) {
        int i = base + j;
        if (i < NN) { start[i] = excl; cursor[i] = excl; excl += v[j]; }
    }
}

__global__ void csr_fill(const int* __restrict__ src, const int* __restrict__ dst,
                         int* __restrict__ cursor, int* __restrict__ eidx) {
    int e = blockIdx.x * blockDim.x + threadIdx.x;
    if (e < EE) {
        int p = atomicAdd(&cursor[dst[e]], 1);
        eidx[p] = src[e];
    }
}

// ================= Weight transpose + bf16 convert =================
__global__ void w_transpose(const float* __restrict__ w, unsigned short* __restrict__ wt) {
    int idx = blockIdx.x * 256 + threadIdx.x;  // n*512 + k, k fastest
    int n = idx >> 9, k = idx & 511;
    wt[idx] = f2b(w[(size_t)k * HH + n]);
}

// ================= Aggregation: bf16 gather, one wave per node =================
__global__ __launch_bounds__(256) void gather_rows_b(
    const unsigned short* __restrict__ xb, const int* __restrict__ start,
    const int* __restrict__ eidx, unsigned short* __restrict__ agg)
{
    int node = blockIdx.x * 4 + (threadIdx.x >> 6);
    if (node >= NN) return;
    int c0 = (threadIdx.x & 63) << 3;   // 8 bf16 per lane
    float a[8] = {0.f,0.f,0.f,0.f,0.f,0.f,0.f,0.f};
    int e1 = start[node + 1];
    for (int e = start[node]; e < e1; ++e) {
        ushort8 v = *(const ushort8*)(xb + (size_t)eidx[e] * HH + c0);
        #pragma unroll
        for (int j = 0; j < 8; ++j) a[j] += b2f(v[j]);
    }
    ushort8 o;
    #pragma unroll
    for (int j = 0; j < 8; ++j) o[j] = f2b(a[j]);
    *(ushort8*)(agg + (size_t)node * HH + c0) = o;
}

// Layer-1 scalar aggregate via CSR
__global__ void gather_scalar(const float* __restrict__ x, const int* __restrict__ start,
                              const int* __restrict__ eidx, float* __restrict__ agg0) {
    int i = blockIdx.x * blockDim.x + threadIdx.x;
    if (i >= NN) return;
    float s = 0.f;
    int e1 = start[i + 1];
    for (int e = start[i]; e < e1; ++e) s += x[eidx[e]];
    agg0[i] = s;
}

// x1[i][h] = relu(agg0[i]*w_rel[h] + b[h] + x[i]*w_root[h]); writes f32 + bf16
__global__ void layer1_expand(const float* __restrict__ x,
                              const float* __restrict__ agg0,
                              const float* __restrict__ w_rel,
                              const float* __restrict__ b,
                              const float* __restrict__ w_root,
                              float* __restrict__ x1,
                              unsigned short* __restrict__ x1b) {
    int idx = blockIdx.x * blockDim.x + threadIdx.x;
    int i = idx >> 7;
    if (i >= NN) return;
    int q = (idx & 127) << 2;
    float a = agg0[i], xv = x[i];
    float4 wr = *(const float4*)&w_rel[q];
    float4 bb = *(const float4*)&b[q];
    float4 wt = *(const float4*)&w_root[q];
    float4 o;
    o.x = fmaxf(fmaf(a, wr.x, fmaf(xv, wt.x, bb.x)), 0.f);
    o.y = fmaxf(fmaf(a, wr.y, fmaf(xv, wt.y, bb.y)), 0.f);
    o.z = fmaxf(fmaf(a, wr.z, fmaf(xv, wt.z, bb.z)), 0.f);
    o.w = fmaxf(fmaf(a, wr.w, fmaf(xv, wt.w, bb.w)), 0.f);
    *(float4*)&x1[(size_t)i * HH + q] = o;
    ushort4 ob = { f2b(o.x), f2b(o.y), f2b(o.z), f2b(o.w) };
    *(ushort4*)&x1b[(size_t)i * HH + q] = ob;
}

// ================= MFMA GEMM — 256x256, counted-vmcnt phase schedule =================
// out = (relu?)(AB@WrT^T + XBp@WoT^T + bias) + resid
// BK=64, 8 waves (2M x 4N, wave tile 128x64), 512 threads, 1 block/CU (by design).
// LDS: 2 K-tile buffers (A[256][64] + B[256][64] bf16 each) = 128 KB.
// Per K-tile: 2 ks-phases of {12 ds_read, lgkmcnt(0), 32 MFMA}; stage t+2 after
// barrier; vmcnt(8) counted wait (never 0 in main loop); setprio around MFMA.
// LDS slot-swizzle: linear dest, pre-swizzled global src s=(l&7)^(l>>3),
// read slot (ks*4+lq)^(l16&7) -> 2 lanes/bank (free).
__device__ inline void gload16(const void* g, void* l) {
    __builtin_amdgcn_global_load_lds(
        (const __attribute__((address_space(1))) unsigned int*)g,
        (__attribute__((address_space(3))) unsigned int*)l,
        16, 0, 0);
}

template<bool RELU, bool RB16, bool WF32, bool WB16>
__global__ __launch_bounds__(512, 2) void gemm_mfma(
    const unsigned short* __restrict__ AB, const unsigned short* __restrict__ XBp,
    const unsigned short* __restrict__ WrT, const unsigned short* __restrict__ WoT,
    const float* __restrict__ bias, const void* __restrict__ residv,
    float* __restrict__ out, unsigned short* __restrict__ outb)
{
    __shared__ unsigned short As[2][256 * 64];   // [buf][row][64k]
    __shared__ unsigned short Bs[2][256 * 64];   // [buf][col][64k]
    const int tid  = threadIdx.x;
    const int wave = tid >> 6, lane = tid & 63;

    // Bijective XCD-chunked mapping (m204): 782 blocks, q=97, r=6.
    const int bid  = blockIdx.x;
    const int xcd  = bid & 7;
    const int cbase = (xcd < 6) ? xcd * 98 : (6 * 98 + (xcd - 6) * 97);
    const int nid  = cbase + (bid >> 3);
    const int col0 = (nid & 1) << 8;   // 2 n-tiles
    const int row0 = (nid >> 1) << 8;

    const int wr = wave >> 2, wc = wave & 3;     // wave tile: rows wr*128, cols wc*64
    const int l16 = lane & 15, lq = lane >> 4;

    // ---- staging geometry: wave covers A rows / B cols [wave*32, wave*32+32)
    const int lsub  = lane >> 3;                         // 0..7 (row within 8-row issue)
    const int lslot = (((lane & 7) ^ lsub) << 3);        // pre-swizzled logical slot (elems)
    int rowAg[4], rowBg[4];
    #pragma unroll
    for (int i = 0; i < 4; ++i) {
        int r = row0 + wave * 32 + i * 8 + lsub;
        rowAg[i] = (r >= NN) ? (NN - 1) : r;
        rowBg[i] = col0 + wave * 32 + i * 8 + lsub;
    }

    // ---- fragment-read slots (linear = logical ^ (row&7); row&7 == l16&7)
    const int rslot0 = (((0 + lq) ^ (l16 & 7)) << 3);    // ks=0
    const int rslot1 = (((4 + lq) ^ (l16 & 7)) << 3);    // ks=1
    const int arow   = (wr * 128 + l16) * 64;            // + m*1024
    const int brow   = (wc * 64  + l16) * 64;            // + n*1024

    f32x4 acc[8][4];
    #pragma unroll
    for (int m = 0; m < 8; ++m)
        #pragma unroll
        for (int n = 0; n < 4; ++n)
            acc[m][n] = (f32x4){0.f, 0.f, 0.f, 0.f};

    auto STAGE = [&](unsigned short* Asb, unsigned short* Bsb, int t) {
        const unsigned short* Ap = (t < 8) ? AB  : XBp;
        const unsigned short* Wp = (t < 8) ? WrT : WoT;
        const int kk = (t & 7) << 6;
        #pragma unroll
        for (int i = 0; i < 4; ++i)
            gload16(Ap + (size_t)rowAg[i] * HH + kk + lslot, Asb + (wave * 32 + i * 8) * 64);
        #pragma unroll
        for (int i = 0; i < 4; ++i)
            gload16(Wp + (size_t)rowBg[i] * HH + kk + lslot, Bsb + (wave * 32 + i * 8) * 64);
    };

    unsigned short *Acur = &As[0][0], *Anxt = &As[1][0];
    unsigned short *Bcur = &Bs[0][0], *Bnxt = &Bs[1][0];

    // Prologue: stage K-tiles 0 and 1; wait only for tile 0 (vmcnt(8)).
    STAGE(Acur, Bcur, 0);
    STAGE(Anxt, Bnxt, 1);
    asm volatile("s_waitcnt vmcnt(8)" ::: "memory");
    __builtin_amdgcn_s_barrier();
    __builtin_amdgcn_sched_barrier(0);

    #pragma unroll 1
    for (int t = 0; t < 16; ++t) {
        // ---- phase ks=0: read frags, compute 32 MFMA
        short8 af0[8], bf0[4];
        #pragma unroll
        for (int m = 0; m < 8; ++m)
            af0[m] = *(const short8*)(Acur + arow + m * 1024 + rslot0);
        #pragma unroll
        for (int n = 0; n < 4; ++n)
            bf0[n] = *(const short8*)(Bcur + brow + n * 1024 + rslot0);
        asm volatile("s_waitcnt lgkmcnt(0)" ::: "memory");
        __builtin_amdgcn_sched_barrier(0);
        __builtin_amdgcn_s_setprio(1);
        #pragma unroll
        for (int m = 0; m < 8; ++m)
            #pragma unroll
            for (int n = 0; n < 4; ++n)
                acc[m][n] = __builtin_amdgcn_mfma_f32_16x16x32_bf16(af0[m], bf0[n], acc[m][n], 0, 0, 0);
        __builtin_amdgcn_s_setprio(0);

        // ---- phase ks=1: read frags (last reads of cur), then barrier + stage
        short8 af1[8], bf1[4];
        #pragma unroll
        for (int m = 0; m < 8; ++m)
            af1[m] = *(const short8*)(Acur + arow + m * 1024 + rslot1);
        #pragma unroll
        for (int n = 0; n < 4; ++n)
            bf1[n] = *(const short8*)(Bcur + brow + n * 1024 + rslot1);
        asm volatile("s_waitcnt lgkmcnt(0)" ::: "memory");
        __builtin_amdgcn_sched_barrier(0);
        __builtin_amdgcn_s_barrier();          // all waves done reading cur
        __builtin_amdgcn_sched_barrier(0);
        if (t < 14) STAGE(Acur, Bcur, t + 2);  // overwrite cur; loads fly under MFMA
        __builtin_amdgcn_sched_barrier(0);
        __builtin_amdgcn_s_setprio(1);
        #pragma unroll
        for (int m = 0; m < 8; ++m)
            #pragma unroll
            for (int n = 0; n < 4; ++n)
                acc[m][n] = __builtin_amdgcn_mfma_f32_16x16x32_bf16(af1[m], bf1[n], acc[m][n], 0, 0, 0);
        __builtin_amdgcn_s_setprio(0);

        if (t < 15) {
            if (t < 14) { asm volatile("s_waitcnt vmcnt(8)" ::: "memory"); }  // t+1 landed, t+2 in flight
            else        { asm volatile("s_waitcnt vmcnt(0)" ::: "memory"); }  // tail drain
            __builtin_amdgcn_s_barrier();      // all waves' t+1 chunks visible
            __builtin_amdgcn_sched_barrier(0);
        }
        unsigned short* tp;
        tp = Acur; Acur = Anxt; Anxt = tp;
        tp = Bcur; Bcur = Bnxt; Bnxt = tp;
    }

    // Epilogue: + bias (+relu) + resid; optional f32 / bf16 stores
    const float*          residf = (const float*)residv;
    const unsigned short* residb = (const unsigned short*)residv;
    float bias_n[4];
    #pragma unroll
    for (int n = 0; n < 4; ++n) bias_n[n] = bias[col0 + wc * 64 + n * 16 + l16];

    #pragma unroll
    for (int m = 0; m < 8; ++m) {
        #pragma unroll
        for (int j = 0; j < 4; ++j) {
            int row = row0 + wr * 128 + m * 16 + lq * 4 + j;
            if (row >= NN) continue;
            #pragma unroll
            for (int n = 0; n < 4; ++n) {
                int col = col0 + wc * 64 + n * 16 + l16;
                size_t off = (size_t)row * HH + col;
                float v = acc[m][n][j] + bias_n[n];
                if (RELU) v = fmaxf(v, 0.f);
                v += RB16 ? b2f(residb[off]) : residf[off];
                if (WF32) out[off] = v;
                if (WB16) outb[off] = f2b(v);
            }
        }
    }
}

extern "C" void kernel_launch(void* const* d_in, const int* in_sizes, int n_in,
                              void* d_out, int out_size, void* d_ws, size_t ws_size,
                              hipStream_t stream) {
    const float* x   = (const float*)d_in[0];
    const int*   ei  = (const int*)d_in[1];
    const int*   src = ei;
    const int*   dst = ei + EE;
    const float* w_rel1  = (const float*)d_in[2];
    const float* b_rel1  = (const float*)d_in[3];
    const float* w_root1 = (const float*)d_in[4];
    const float* w_rel2  = (const float*)d_in[5];
    const float* b_rel2  = (const float*)d_in[6];
    const float* w_root2 = (const float*)d_in[7];
    const float* w_rel3  = (const float*)d_in[8];
    const float* b_rel3  = (const float*)d_in[9];
    const float* w_root3 = (const float*)d_in[10];
    const float* w_rel4  = (const float*)d_in[11];
    const float* b_rel4  = (const float*)d_in[12];
    const float* w_root4 = (const float*)d_in[13];

    const size_t NH = (size_t)NN * HH;
    float*          W0   = (float*)d_ws;                 // x1 (f32), then x3 (f32)
    unsigned short* XB   = (unsigned short*)(W0 + NH);   // bf16 ping (x1, then x3)
    unsigned short* XB2  = XB + NH;                      // bf16 pong (x2)
    unsigned short* AGB  = XB2 + NH;                     // agg bf16
    unsigned short* WT   = AGB + NH;                     // 6 transposed bf16 weights
    float*          agg0 = (float*)(WT + 6 * 262144);
    int*            csr  = (int*)(agg0 + NN);
    int* deg       = csr;
    int* start     = csr + NN;
    int* cursor    = start + NN + 1;
    int* eidx      = cursor + NN;
    int* blockSums = eidx + EE;
    float* out = (float*)d_out;

    unsigned short* WrT2 = WT;
    unsigned short* WoT2 = WT + 1 * 262144;
    unsigned short* WrT3 = WT + 2 * 262144;
    unsigned short* WoT3 = WT + 3 * 262144;
    unsigned short* WrT4 = WT + 4 * 262144;
    unsigned short* WoT4 = WT + 5 * 262144;

    const int gGemm = 782;   // 391 m-tiles x 2 n-tiles (256x256), XCD-chunked in-kernel

    // ---- CSR build ----
    hipMemsetAsync(deg, 0, NN * sizeof(int), stream);
    histo_deg<<<(EE + 255) / 256, 256, 0, stream>>>(dst, deg);
    scan_reduce<<<NB_SCAN, 256, 0, stream>>>(deg, blockSums);
    scan_top<<<1, 128, 0, stream>>>(blockSums, start);
    scan_down<<<NB_SCAN, 256, 0, stream>>>(deg, blockSums, start, cursor);
    csr_fill<<<(EE + 255) / 256, 256, 0, stream>>>(src, dst, cursor, eidx);

    // ---- Weights -> transposed bf16 ----
    w_transpose<<<1024, 256, 0, stream>>>(w_rel2,  WrT2);
    w_transpose<<<1024, 256, 0, stream>>>(w_root2, WoT2);
    w_transpose<<<1024, 256, 0, stream>>>(w_rel3,  WrT3);
    w_transpose<<<1024, 256, 0, stream>>>(w_root3, WoT3);
    w_transpose<<<1024, 256, 0, stream>>>(w_rel4,  WrT4);
    w_transpose<<<1024, 256, 0, stream>>>(w_root4, WoT4);

    // ---- Layer 1: x1 -> W0 (f32) + XB (bf16) ----
    gather_scalar<<<(NN + 255) / 256, 256, 0, stream>>>(x, start, eidx, agg0);
    layer1_expand<<<50000, 256, 0, stream>>>(x, agg0, w_rel1, b_rel1, w_root1, W0, XB);

    // ---- Layer 2: x2 = relu(conv(x1)) + x1 -> XB2 (bf16 only) ----
    gather_rows_b<<<25000, 256, 0, stream>>>(XB, start, eidx, AGB);
    gemm_mfma<true, false, false, true><<<gGemm, 512, 0, stream>>>(
        AGB, XB, WrT2, WoT2, b_rel2, W0, nullptr, XB2);

    // ---- Layer 3: x3 = conv(x2) + x2 -> W0 (f32) + XB (bf16); resid = bf16 x2 ----
    gather_rows_b<<<25000, 256, 0, stream>>>(XB2, start, eidx, AGB);
    gemm_mfma<false, true, true, true><<<gGemm, 512, 0, stream>>>(
        AGB, XB2, WrT3, WoT3, b_rel3, XB2, W0, XB);

    // ---- Layer 4: x4 = conv(x3) + x3 -> d_out (f32); resid = f32 x3 ----
    gather_rows_b<<<25000, 256, 0, stream>>>(XB, start, eidx, AGB);
    gemm_mfma<false, false, true, false><<<gGemm, 512, 0, stream>>>(
        AGB, XB, WrT4, WoT4, b_rel4, W0, out, nullptr);
}

// Round 10
// 811.565 us; speedup vs baseline: 2.0750x; 1.2839x over previous
//
#include <hip/hip_runtime.h>

#define NN 100000
#define EE 400000
#define HH 512
#define NB_SCAN 98   // ceil(NN/1024)

typedef __attribute__((ext_vector_type(8))) short short8;
typedef __attribute__((ext_vector_type(8))) unsigned short ushort8;
typedef __attribute__((ext_vector_type(4))) float f32x4;

__device__ inline unsigned short f2b(float f) {   // f32 -> bf16 RNE
    unsigned int u = __float_as_uint(f);
    return (unsigned short)((u + 0x7fffu + ((u >> 16) & 1u)) >> 16);
}
__device__ inline float b2f(unsigned short b) {
    return __uint_as_float(((unsigned int)b) << 16);
}

// ================= CSR build =================
__global__ void histo_deg(const int* __restrict__ dst, int* __restrict__ deg) {
    int e = blockIdx.x * blockDim.x + threadIdx.x;
    if (e < EE) atomicAdd(&deg[dst[e]], 1);
}

__global__ void scan_reduce(const int* __restrict__ deg, int* __restrict__ blockSums) {
    __shared__ int s[256];
    int b = blockIdx.x, t = threadIdx.x;
    int base = b * 1024 + t * 4;
    int v = 0;
    #pragma unroll
    for (int j = 0; j < 4; ++j) { int i = base + j; if (i < NN) v += deg[i]; }
    s[t] = v; __syncthreads();
    for (int off = 128; off > 0; off >>= 1) {
        if (t < off) s[t] += s[t + off];
        __syncthreads();
    }
    if (t == 0) blockSums[b] = s[0];
}

__global__ void scan_top(int* __restrict__ blockSums, int* __restrict__ start) {
    __shared__ int s[128];
    int t = threadIdx.x;
    s[t] = (t < NB_SCAN) ? blockSums[t] : 0;
    __syncthreads();
    for (int off = 1; off < 128; off <<= 1) {
        int u = (t >= off) ? s[t - off] : 0;
        __syncthreads();
        s[t] += u;
        __syncthreads();
    }
    if (t < NB_SCAN) blockSums[t] = (t == 0) ? 0 : s[t - 1];  // exclusive
    if (t == 0) start[NN] = EE;
}

__global__ void scan_down(const int* __restrict__ deg, const int* __restrict__ blockSums,
                          int* __restrict__ start, int* __restrict__ cursor) {
    __shared__ int s[256];
    int b = blockIdx.x, t = threadIdx.x;
    int base = b * 1024 + t * 4;
    int v[4]; int sum = 0;
    #pragma unroll
    for (int j = 0; j < 4; ++j) {
        int i = base + j;
        v[j] = (i < NN) ? deg[i] : 0;
        sum += v[j];
    }
    s[t] = sum; __syncthreads();
    for (int off = 1; off < 256; off <<= 1) {
        int u = (t >= off) ? s[t - off] : 0;
        __syncthreads();
        s[t] += u;
        __syncthreads();
    }
    int excl = blockSums[b] + ((t == 0) ? 0 : s[t - 1]);
    #pragma unroll
    for (int j = 0; j < 4; ++j) {
        int i = base + j;
        if (i < NN) { start[i] = excl; cursor[i] = excl; excl += v[j]; }
    }
}

__global__ void csr_fill(const int* __restrict__ src, const int* __restrict__ dst,
                         int* __restrict__ cursor, int* __restrict__ eidx) {
    int e = blockIdx.x * blockDim.x + threadIdx.x;
    if (e < EE) {
        int p = atomicAdd(&cursor[dst[e]], 1);
        eidx[p] = src[e];
    }
}

// ================= Weight transpose + bf16 convert =================
__global__ void w_transpose(const float* __restrict__ w, unsigned short* __restrict__ wt) {
    int idx = blockIdx.x * 256 + threadIdx.x;  // n*512 + k, k fastest
    int n = idx >> 9, k = idx & 511;
    wt[idx] = f2b(w[(size_t)k * HH + n]);
}

// ================= Aggregation: bf16 gather, one wave per node =================
// 4-deep software pipeline: issue 4 independent row loads per iteration (MLP).
__global__ __launch_bounds__(256) void gather_rows_b(
    const unsigned short* __restrict__ xb, const int* __restrict__ start,
    const int* __restrict__ eidx, unsigned short* __restrict__ agg)
{
    int node = blockIdx.x * 4 + (threadIdx.x >> 6);
    if (node >= NN) return;
    int c0 = (threadIdx.x & 63) << 3;   // 8 bf16 per lane
    float a[8] = {0.f,0.f,0.f,0.f,0.f,0.f,0.f,0.f};
    int e0 = start[node], e1 = start[node + 1];
    int e = e0;
    for (; e + 4 <= e1; e += 4) {
        int s0 = eidx[e], s1 = eidx[e + 1], s2 = eidx[e + 2], s3 = eidx[e + 3];
        ushort8 v0 = *(const ushort8*)(xb + (size_t)s0 * HH + c0);
        ushort8 v1 = *(const ushort8*)(xb + (size_t)s1 * HH + c0);
        ushort8 v2 = *(const ushort8*)(xb + (size_t)s2 * HH + c0);
        ushort8 v3 = *(const ushort8*)(xb + (size_t)s3 * HH + c0);
        #pragma unroll
        for (int j = 0; j < 8; ++j)
            a[j] += (b2f(v0[j]) + b2f(v1[j])) + (b2f(v2[j]) + b2f(v3[j]));
    }
    for (; e < e1; ++e) {
        ushort8 v = *(const ushort8*)(xb + (size_t)eidx[e] * HH + c0);
        #pragma unroll
        for (int j = 0; j < 8; ++j) a[j] += b2f(v[j]);
    }
    ushort8 o;
    #pragma unroll
    for (int j = 0; j < 8; ++j) o[j] = f2b(a[j]);
    *(ushort8*)(agg + (size_t)node * HH + c0) = o;
}

// Layer-1 scalar aggregate via CSR
__global__ void gather_scalar(const float* __restrict__ x, const int* __restrict__ start,
                              const int* __restrict__ eidx, float* __restrict__ agg0) {
    int i = blockIdx.x * blockDim.x + threadIdx.x;
    if (i >= NN) return;
    float s = 0.f;
    int e1 = start[i + 1];
    for (int e = start[i]; e < e1; ++e) s += x[eidx[e]];
    agg0[i] = s;
}

// x1[i][h] = relu(agg0[i]*w_rel[h] + b[h] + x[i]*w_root[h]); bf16 output only
__global__ void layer1_expand(const float* __restrict__ x,
                              const float* __restrict__ agg0,
                              const float* __restrict__ w_rel,
                              const float* __restrict__ b,
                              const float* __restrict__ w_root,
                              unsigned short* __restrict__ x1b) {
    int idx = blockIdx.x * blockDim.x + threadIdx.x;
    int i = idx >> 7;
    if (i >= NN) return;
    int q = (idx & 127) << 2;
    float a = agg0[i], xv = x[i];
    float4 wr = *(const float4*)&w_rel[q];
    float4 bb = *(const float4*)&b[q];
    float4 wt = *(const float4*)&w_root[q];
    float4 o;
    o.x = fmaxf(fmaf(a, wr.x, fmaf(xv, wt.x, bb.x)), 0.f);
    o.y = fmaxf(fmaf(a, wr.y, fmaf(xv, wt.y, bb.y)), 0.f);
    o.z = fmaxf(fmaf(a, wr.z, fmaf(xv, wt.z, bb.z)), 0.f);
    o.w = fmaxf(fmaf(a, wr.w, fmaf(xv, wt.w, bb.w)), 0.f);
    ushort4 ob = { f2b(o.x), f2b(o.y), f2b(o.z), f2b(o.w) };
    *(ushort4*)&x1b[(size_t)i * HH + q] = ob;
}

// ================= MFMA GEMM (R5 structure — empirically best) =================
// out = (relu?)(AB@WrT^T + XBp@WoT^T + bias) + resid(bf16)
// 128x128 tile, BK=32, 4 waves, double-buffered LDS (stage next buf before
// compute, ONE barrier per K-step). LDS k-slots XOR-swizzled both sides
// (verified conflict-free R4-R9). Residual is always bf16; output is
// bf16 (F32OUT=false) or f32 (F32OUT=true).
__device__ inline void gload16(const void* g, void* l) {
    __builtin_amdgcn_global_load_lds(
        (const __attribute__((address_space(1))) unsigned int*)g,
        (__attribute__((address_space(3))) unsigned int*)l,
        16, 0, 0);
}

template<bool RELU, bool F32OUT>
__global__ __launch_bounds__(256, 3) void gemm_mfma(
    const unsigned short* __restrict__ AB, const unsigned short* __restrict__ XBp,
    const unsigned short* __restrict__ WrT, const unsigned short* __restrict__ WoT,
    const float* __restrict__ bias, const unsigned short* __restrict__ residb,
    float* __restrict__ out, unsigned short* __restrict__ outb)
{
    __shared__ unsigned short As[2 * 128 * 32];  // [buf][row][k], k-slots swizzled
    __shared__ unsigned short Bs[2 * 128 * 32];  // [buf][col][k]
    const int tid  = threadIdx.x;
    const int wave = tid >> 6, lane = tid & 63;

    // Bijective XCD-chunked mapping: 3128 blocks = 8 XCDs x 391.
    const int bid = blockIdx.x;
    const int nid = (bid & 7) * 391 + (bid >> 3);
    const int col0 = (nid & 3) << 7;   // n-tile fastest within chunk -> A-panel L2 reuse
    const int row0 = (nid >> 2) << 7;

    const int wr = wave >> 1, wc = wave & 1; // wave's 64x64 quadrant
    const int l16 = lane & 15, lq = lane >> 4;
    const int sRow = lane >> 2;                                  // staging row in chunk
    const int sColSwz = (((lane & 3) ^ ((lane >> 3) & 3)) << 3); // swizzled src k-slot (shorts)
    const int xorslot = ((lq ^ ((lane >> 1) & 3)) << 3);         // read-side slot (shorts)

    // Staged global rows/cols (clamped; stores guarded)
    int rowA[2], colB[2];
    #pragma unroll
    for (int i = 0; i < 2; ++i) {
        int chunk = (wave << 1) + i;
        int gr = row0 + chunk * 16 + sRow;
        rowA[i] = (gr >= NN) ? (NN - 1) : gr;
        colB[i] = col0 + chunk * 16 + sRow;
    }

    f32x4 acc[4][4];
    #pragma unroll
    for (int m = 0; m < 4; ++m)
        #pragma unroll
        for (int n = 0; n < 4; ++n)
            acc[m][n] = (f32x4){0.f, 0.f, 0.f, 0.f};

    auto STAGE = [&](unsigned short* Asb, unsigned short* Bsb, int t) {
        const int k0 = t << 5;
        const unsigned short* Ap = (k0 < 512) ? AB  : XBp;
        const unsigned short* Wp = (k0 < 512) ? WrT : WoT;
        const int kk = k0 & 511;
        #pragma unroll
        for (int i = 0; i < 2; ++i) {
            int chunk = (wave << 1) + i;
            gload16(Ap + (size_t)rowA[i] * HH + kk + sColSwz, Asb + chunk * 512);
            gload16(Wp + (size_t)colB[i] * HH + kk + sColSwz, Bsb + chunk * 512);
        }
    };

    auto COMPUTE = [&](const unsigned short* Asb, const unsigned short* Bsb) {
        short8 af[4], bfv[4];
        #pragma unroll
        for (int m = 0; m < 4; ++m)
            af[m] = *(const short8*)(Asb + (wr * 64 + m * 16 + l16) * 32 + xorslot);
        #pragma unroll
        for (int n = 0; n < 4; ++n)
            bfv[n] = *(const short8*)(Bsb + (wc * 64 + n * 16 + l16) * 32 + xorslot);
        #pragma unroll
        for (int m = 0; m < 4; ++m)
            #pragma unroll
            for (int n = 0; n < 4; ++n)
                acc[m][n] = __builtin_amdgcn_mfma_f32_16x16x32_bf16(af[m], bfv[n], acc[m][n], 0, 0, 0);
    };

    unsigned short* A0 = As;        unsigned short* A1 = As + 4096;
    unsigned short* B0 = Bs;        unsigned short* B1 = Bs + 4096;

    STAGE(A0, B0, 0);
    __syncthreads();                       // drains vmcnt(0): tile 0 resident
    #pragma unroll 1
    for (int t = 0; t < 32; t += 2) {
        STAGE(A1, B1, t + 1);              // prefetch next tile (hidden under compute)
        COMPUTE(A0, B0);
        __syncthreads();                   // next staged + everyone done with buf0
        if (t + 2 < 32) STAGE(A0, B0, t + 2);
        COMPUTE(A1, B1);
        __syncthreads();
    }

    // Epilogue: + bias (+relu) + bf16 resid; store f32 or bf16
    float bias_n[4];
    #pragma unroll
    for (int n = 0; n < 4; ++n) bias_n[n] = bias[col0 + wc * 64 + n * 16 + l16];

    #pragma unroll
    for (int m = 0; m < 4; ++m) {
        #pragma unroll
        for (int j = 0; j < 4; ++j) {
            int row = row0 + wr * 64 + m * 16 + lq * 4 + j;
            if (row >= NN) continue;
            #pragma unroll
            for (int n = 0; n < 4; ++n) {
                int col = col0 + wc * 64 + n * 16 + l16;
                size_t off = (size_t)row * HH + col;
                float v = acc[m][n][j] + bias_n[n];
                if (RELU) v = fmaxf(v, 0.f);
                v += b2f(residb[off]);
                if (F32OUT) out[off] = v;
                else        outb[off] = f2b(v);
            }
        }
    }
}

extern "C" void kernel_launch(void* const* d_in, const int* in_sizes, int n_in,
                              void* d_out, int out_size, void* d_ws, size_t ws_size,
                              hipStream_t stream) {
    const float* x   = (const float*)d_in[0];
    const int*   ei  = (const int*)d_in[1];
    const int*   src = ei;
    const int*   dst = ei + EE;
    const float* w_rel1  = (const float*)d_in[2];
    const float* b_rel1  = (const float*)d_in[3];
    const float* w_root1 = (const float*)d_in[4];
    const float* w_rel2  = (const float*)d_in[5];
    const float* b_rel2  = (const float*)d_in[6];
    const float* w_root2 = (const float*)d_in[7];
    const float* w_rel3  = (const float*)d_in[8];
    const float* b_rel3  = (const float*)d_in[9];
    const float* w_root3 = (const float*)d_in[10];
    const float* w_rel4  = (const float*)d_in[11];
    const float* b_rel4  = (const float*)d_in[12];
    const float* w_root4 = (const float*)d_in[13];

    const size_t NH = (size_t)NN * HH;
    unsigned short* XB   = (unsigned short*)d_ws;        // x1 bf16
    unsigned short* XB2  = XB + NH;                      // x2 bf16
    unsigned short* X3B  = XB2 + NH;                     // x3 bf16
    unsigned short* AGB  = X3B + NH;                     // agg bf16
    unsigned short* WT   = AGB + NH;                     // 6 transposed bf16 weights
    float*          agg0 = (float*)(WT + 6 * 262144);
    int*            csr  = (int*)(agg0 + NN);
    int* deg       = csr;
    int* start     = csr + NN;
    int* cursor    = start + NN + 1;
    int* eidx      = cursor + NN;
    int* blockSums = eidx + EE;
    float* out = (float*)d_out;

    unsigned short* WrT2 = WT;
    unsigned short* WoT2 = WT + 1 * 262144;
    unsigned short* WrT3 = WT + 2 * 262144;
    unsigned short* WoT3 = WT + 3 * 262144;
    unsigned short* WrT4 = WT + 4 * 262144;
    unsigned short* WoT4 = WT + 5 * 262144;

    const int gGemm = 3128;  // 782 m-tiles x 4 n-tiles (128x128), XCD-chunked in-kernel

    // ---- CSR build ----
    hipMemsetAsync(deg, 0, NN * sizeof(int), stream);
    histo_deg<<<(EE + 255) / 256, 256, 0, stream>>>(dst, deg);
    scan_reduce<<<NB_SCAN, 256, 0, stream>>>(deg, blockSums);
    scan_top<<<1, 128, 0, stream>>>(blockSums, start);
    scan_down<<<NB_SCAN, 256, 0, stream>>>(deg, blockSums, start, cursor);
    csr_fill<<<(EE + 255) / 256, 256, 0, stream>>>(src, dst, cursor, eidx);

    // ---- Weights -> transposed bf16 ----
    w_transpose<<<1024, 256, 0, stream>>>(w_rel2,  WrT2);
    w_transpose<<<1024, 256, 0, stream>>>(w_root2, WoT2);
    w_transpose<<<1024, 256, 0, stream>>>(w_rel3,  WrT3);
    w_transpose<<<1024, 256, 0, stream>>>(w_root3, WoT3);
    w_transpose<<<1024, 256, 0, stream>>>(w_rel4,  WrT4);
    w_transpose<<<1024, 256, 0, stream>>>(w_root4, WoT4);

    // ---- Layer 1: x1 -> XB (bf16) ----
    gather_scalar<<<(NN + 255) / 256, 256, 0, stream>>>(x, start, eidx, agg0);
    layer1_expand<<<50000, 256, 0, stream>>>(x, agg0, w_rel1, b_rel1, w_root1, XB);

    // ---- Layer 2: x2 = relu(conv(x1)) + x1 -> XB2 (bf16) ----
    gather_rows_b<<<25000, 256, 0, stream>>>(XB, start, eidx, AGB);
    gemm_mfma<true, false><<<gGemm, 256, 0, stream>>>(
        AGB, XB, WrT2, WoT2, b_rel2, XB, nullptr, XB2);

    // ---- Layer 3: x3 = conv(x2) + x2 -> X3B (bf16) ----
    gather_rows_b<<<25000, 256, 0, stream>>>(XB2, start, eidx, AGB);
    gemm_mfma<false, false><<<gGemm, 256, 0, stream>>>(
        AGB, XB2, WrT3, WoT3, b_rel3, XB2, nullptr, X3B);

    // ---- Layer 4: x4 = conv(x3) + x3 -> d_out (f32) ----
    gather_rows_b<<<25000, 256, 0, stream>>>(X3B, start, eidx, AGB);
    gemm_mfma<false, true><<<gGemm, 256, 0, stream>>>(
        AGB, X3B, WrT4, WoT4, b_rel4, X3B, out, nullptr);
}

// Round 11
// 810.624 us; speedup vs baseline: 2.0774x; 1.0012x over previous
//
#include <hip/hip_runtime.h>

#define NN 100000
#define EE 400000
#define HH 512
#define NB_SCAN 98   // ceil(NN/1024)

typedef __attribute__((ext_vector_type(8))) short short8;
typedef __attribute__((ext_vector_type(8))) unsigned short ushort8;
typedef __attribute__((ext_vector_type(4))) float f32x4;

__device__ inline unsigned short f2b(float f) {   // f32 -> bf16 RNE
    unsigned int u = __float_as_uint(f);
    return (unsigned short)((u + 0x7fffu + ((u >> 16) & 1u)) >> 16);
}
__device__ inline float b2f(unsigned short b) {
    return __uint_as_float(((unsigned int)b) << 16);
}

// ================= CSR build =================
__global__ void histo_deg(const int* __restrict__ dst, int* __restrict__ deg) {
    int e = blockIdx.x * blockDim.x + threadIdx.x;
    if (e < EE) atomicAdd(&deg[dst[e]], 1);
}

__global__ void scan_reduce(const int* __restrict__ deg, int* __restrict__ blockSums) {
    __shared__ int s[256];
    int b = blockIdx.x, t = threadIdx.x;
    int base = b * 1024 + t * 4;
    int v = 0;
    #pragma unroll
    for (int j = 0; j < 4; ++j) { int i = base + j; if (i < NN) v += deg[i]; }
    s[t] = v; __syncthreads();
    for (int off = 128; off > 0; off >>= 1) {
        if (t < off) s[t] += s[t + off];
        __syncthreads();
    }
    if (t == 0) blockSums[b] = s[0];
}

__global__ void scan_top(int* __restrict__ blockSums, int* __restrict__ start) {
    __shared__ int s[128];
    int t = threadIdx.x;
    s[t] = (t < NB_SCAN) ? blockSums[t] : 0;
    __syncthreads();
    for (int off = 1; off < 128; off <<= 1) {
        int u = (t >= off) ? s[t - off] : 0;
        __syncthreads();
        s[t] += u;
        __syncthreads();
    }
    if (t < NB_SCAN) blockSums[t] = (t == 0) ? 0 : s[t - 1];  // exclusive
    if (t == 0) start[NN] = EE;
}

__global__ void scan_down(const int* __restrict__ deg, const int* __restrict__ blockSums,
                          int* __restrict__ start, int* __restrict__ cursor) {
    __shared__ int s[256];
    int b = blockIdx.x, t = threadIdx.x;
    int base = b * 1024 + t * 4;
    int v[4]; int sum = 0;
    #pragma unroll
    for (int j = 0; j < 4; ++j) {
        int i = base + j;
        v[j] = (i < NN) ? deg[i] : 0;
        sum += v[j];
    }
    s[t] = sum; __syncthreads();
    for (int off = 1; off < 256; off <<= 1) {
        int u = (t >= off) ? s[t - off] : 0;
        __syncthreads();
        s[t] += u;
        __syncthreads();
    }
    int excl = blockSums[b] + ((t == 0) ? 0 : s[t - 1]);
    #pragma unroll
    for (int j = 0; j < 4; ++j) {
        int i = base + j;
        if (i < NN) { start[i] = excl; cursor[i] = excl; excl += v[j]; }
    }
}

__global__ void csr_fill(const int* __restrict__ src, const int* __restrict__ dst,
                         int* __restrict__ cursor, int* __restrict__ eidx) {
    int e = blockIdx.x * blockDim.x + threadIdx.x;
    if (e < EE) {
        int p = atomicAdd(&cursor[dst[e]], 1);
        eidx[p] = src[e];
    }
}

// ================= Weight transpose + bf16 convert =================
__global__ void w_transpose(const float* __restrict__ w, unsigned short* __restrict__ wt) {
    int idx = blockIdx.x * 256 + threadIdx.x;  // n*512 + k, k fastest
    int n = idx >> 9, k = idx & 511;
    wt[idx] = f2b(w[(size_t)k * HH + n]);
}

// ================= Aggregation: bf16 gather, one wave per node =================
// 4-deep software pipeline: issue 4 independent row loads per iteration (MLP).
__global__ __launch_bounds__(256) void gather_rows_b(
    const unsigned short* __restrict__ xb, const int* __restrict__ start,
    const int* __restrict__ eidx, unsigned short* __restrict__ agg)
{
    int node = blockIdx.x * 4 + (threadIdx.x >> 6);
    if (node >= NN) return;
    int c0 = (threadIdx.x & 63) << 3;   // 8 bf16 per lane
    float a[8] = {0.f,0.f,0.f,0.f,0.f,0.f,0.f,0.f};
    int e0 = start[node], e1 = start[node + 1];
    int e = e0;
    for (; e + 4 <= e1; e += 4) {
        int s0 = eidx[e], s1 = eidx[e + 1], s2 = eidx[e + 2], s3 = eidx[e + 3];
        ushort8 v0 = *(const ushort8*)(xb + (size_t)s0 * HH + c0);
        ushort8 v1 = *(const ushort8*)(xb + (size_t)s1 * HH + c0);
        ushort8 v2 = *(const ushort8*)(xb + (size_t)s2 * HH + c0);
        ushort8 v3 = *(const ushort8*)(xb + (size_t)s3 * HH + c0);
        #pragma unroll
        for (int j = 0; j < 8; ++j)
            a[j] += (b2f(v0[j]) + b2f(v1[j])) + (b2f(v2[j]) + b2f(v3[j]));
    }
    for (; e < e1; ++e) {
        ushort8 v = *(const ushort8*)(xb + (size_t)eidx[e] * HH + c0);
        #pragma unroll
        for (int j = 0; j < 8; ++j) a[j] += b2f(v[j]);
    }
    ushort8 o;
    #pragma unroll
    for (int j = 0; j < 8; ++j) o[j] = f2b(a[j]);
    *(ushort8*)(agg + (size_t)node * HH + c0) = o;
}

// Layer-1 scalar aggregate via CSR
__global__ void gather_scalar(const float* __restrict__ x, const int* __restrict__ start,
                              const int* __restrict__ eidx, float* __restrict__ agg0) {
    int i = blockIdx.x * blockDim.x + threadIdx.x;
    if (i >= NN) return;
    float s = 0.f;
    int e1 = start[i + 1];
    for (int e = start[i]; e < e1; ++e) s += x[eidx[e]];
    agg0[i] = s;
}

// x1[i][h] = relu(agg0[i]*w_rel[h] + b[h] + x[i]*w_root[h]); bf16 output only
__global__ void layer1_expand(const float* __restrict__ x,
                              const float* __restrict__ agg0,
                              const float* __restrict__ w_rel,
                              const float* __restrict__ b,
                              const float* __restrict__ w_root,
                              unsigned short* __restrict__ x1b) {
    int idx = blockIdx.x * blockDim.x + threadIdx.x;
    int i = idx >> 7;
    if (i >= NN) return;
    int q = (idx & 127) << 2;
    float a = agg0[i], xv = x[i];
    float4 wr = *(const float4*)&w_rel[q];
    float4 bb = *(const float4*)&b[q];
    float4 wt = *(const float4*)&w_root[q];
    float4 o;
    o.x = fmaxf(fmaf(a, wr.x, fmaf(xv, wt.x, bb.x)), 0.f);
    o.y = fmaxf(fmaf(a, wr.y, fmaf(xv, wt.y, bb.y)), 0.f);
    o.z = fmaxf(fmaf(a, wr.z, fmaf(xv, wt.z, bb.z)), 0.f);
    o.w = fmaxf(fmaf(a, wr.w, fmaf(xv, wt.w, bb.w)), 0.f);
    ushort4 ob = { f2b(o.x), f2b(o.y), f2b(o.z), f2b(o.w) };
    *(ushort4*)&x1b[(size_t)i * HH + q] = ob;
}

// ================= MFMA GEMM (R10 structure, 4 blocks/CU) =================
// out = (relu?)(AB@WrT^T + XBp@WoT^T + bias) + resid(bf16)
// 128x128 tile, BK=32, 4 waves, double-buffered LDS (stage next buf before
// compute, ONE barrier per K-step). LDS k-slots XOR-swizzled both sides
// (verified conflict-free R4-R10). Latency-bound -> occupancy is the lever:
// 4 blocks/CU (LDS 4x32=128<=160 KB; regs 56+64acc=120/wave, 16x120=1920<=2048).
__device__ inline void gload16(const void* g, void* l) {
    __builtin_amdgcn_global_load_lds(
        (const __attribute__((address_space(1))) unsigned int*)g,
        (__attribute__((address_space(3))) unsigned int*)l,
        16, 0, 0);
}

template<bool RELU, bool F32OUT>
__global__ __launch_bounds__(256, 4) void gemm_mfma(
    const unsigned short* __restrict__ AB, const unsigned short* __restrict__ XBp,
    const unsigned short* __restrict__ WrT, const unsigned short* __restrict__ WoT,
    const float* __restrict__ bias, const unsigned short* __restrict__ residb,
    float* __restrict__ out, unsigned short* __restrict__ outb)
{
    __shared__ unsigned short As[2 * 128 * 32];  // [buf][row][k], k-slots swizzled
    __shared__ unsigned short Bs[2 * 128 * 32];  // [buf][col][k]
    const int tid  = threadIdx.x;
    const int wave = tid >> 6, lane = tid & 63;

    // Bijective XCD-chunked mapping: 3128 blocks = 8 XCDs x 391.
    const int bid = blockIdx.x;
    const int nid = (bid & 7) * 391 + (bid >> 3);
    const int col0 = (nid & 3) << 7;   // n-tile fastest within chunk -> A-panel L2 reuse
    const int row0 = (nid >> 2) << 7;

    const int wr = wave >> 1, wc = wave & 1; // wave's 64x64 quadrant
    const int l16 = lane & 15, lq = lane >> 4;
    const int sRow = lane >> 2;                                  // staging row in chunk
    const int sColSwz = (((lane & 3) ^ ((lane >> 3) & 3)) << 3); // swizzled src k-slot (shorts)
    const int xorslot = ((lq ^ ((lane >> 1) & 3)) << 3);         // read-side slot (shorts)

    // Staged global rows/cols (clamped; stores guarded)
    int rowA[2], colB[2];
    #pragma unroll
    for (int i = 0; i < 2; ++i) {
        int chunk = (wave << 1) + i;
        int gr = row0 + chunk * 16 + sRow;
        rowA[i] = (gr >= NN) ? (NN - 1) : gr;
        colB[i] = col0 + chunk * 16 + sRow;
    }

    f32x4 acc[4][4];
    #pragma unroll
    for (int m = 0; m < 4; ++m)
        #pragma unroll
        for (int n = 0; n < 4; ++n)
            acc[m][n] = (f32x4){0.f, 0.f, 0.f, 0.f};

    auto STAGE = [&](unsigned short* Asb, unsigned short* Bsb, int t) {
        const int k0 = t << 5;
        const unsigned short* Ap = (k0 < 512) ? AB  : XBp;
        const unsigned short* Wp = (k0 < 512) ? WrT : WoT;
        const int kk = k0 & 511;
        #pragma unroll
        for (int i = 0; i < 2; ++i) {
            int chunk = (wave << 1) + i;
            gload16(Ap + (size_t)rowA[i] * HH + kk + sColSwz, Asb + chunk * 512);
            gload16(Wp + (size_t)colB[i] * HH + kk + sColSwz, Bsb + chunk * 512);
        }
    };

    auto COMPUTE = [&](const unsigned short* Asb, const unsigned short* Bsb) {
        short8 af[4], bfv[4];
        #pragma unroll
        for (int m = 0; m < 4; ++m)
            af[m] = *(const short8*)(Asb + (wr * 64 + m * 16 + l16) * 32 + xorslot);
        #pragma unroll
        for (int n = 0; n < 4; ++n)
            bfv[n] = *(const short8*)(Bsb + (wc * 64 + n * 16 + l16) * 32 + xorslot);
        #pragma unroll
        for (int m = 0; m < 4; ++m)
            #pragma unroll
            for (int n = 0; n < 4; ++n)
                acc[m][n] = __builtin_amdgcn_mfma_f32_16x16x32_bf16(af[m], bfv[n], acc[m][n], 0, 0, 0);
    };

    unsigned short* A0 = As;        unsigned short* A1 = As + 4096;
    unsigned short* B0 = Bs;        unsigned short* B1 = Bs + 4096;

    STAGE(A0, B0, 0);
    __syncthreads();                       // drains vmcnt(0): tile 0 resident
    #pragma unroll 1
    for (int t = 0; t < 32; t += 2) {
        STAGE(A1, B1, t + 1);              // prefetch next tile (hidden under compute)
        COMPUTE(A0, B0);
        __syncthreads();                   // next staged + everyone done with buf0
        if (t + 2 < 32) STAGE(A0, B0, t + 2);
        COMPUTE(A1, B1);
        __syncthreads();
    }

    // Epilogue: + bias (+relu) + bf16 resid; store f32 or bf16
    float bias_n[4];
    #pragma unroll
    for (int n = 0; n < 4; ++n) bias_n[n] = bias[col0 + wc * 64 + n * 16 + l16];

    #pragma unroll
    for (int m = 0; m < 4; ++m) {
        #pragma unroll
        for (int j = 0; j < 4; ++j) {
            int row = row0 + wr * 64 + m * 16 + lq * 4 + j;
            if (row >= NN) continue;
            #pragma unroll
            for (int n = 0; n < 4; ++n) {
                int col = col0 + wc * 64 + n * 16 + l16;
                size_t off = (size_t)row * HH + col;
                float v = acc[m][n][j] + bias_n[n];
                if (RELU) v = fmaxf(v, 0.f);
                v += b2f(residb[off]);
                if (F32OUT) out[off] = v;
                else        outb[off] = f2b(v);
            }
        }
    }
}

extern "C" void kernel_launch(void* const* d_in, const int* in_sizes, int n_in,
                              void* d_out, int out_size, void* d_ws, size_t ws_size,
                              hipStream_t stream) {
    const float* x   = (const float*)d_in[0];
    const int*   ei  = (const int*)d_in[1];
    const int*   src = ei;
    const int*   dst = ei + EE;
    const float* w_rel1  = (const float*)d_in[2];
    const float* b_rel1  = (const float*)d_in[3];
    const float* w_root1 = (const float*)d_in[4];
    const float* w_rel2  = (const float*)d_in[5];
    const float* b_rel2  = (const float*)d_in[6];
    const float* w_root2 = (const float*)d_in[7];
    const float* w_rel3  = (const float*)d_in[8];
    const float* b_rel3  = (const float*)d_in[9];
    const float* w_root3 = (const float*)d_in[10];
    const float* w_rel4  = (const float*)d_in[11];
    const float* b_rel4  = (const float*)d_in[12];
    const float* w_root4 = (const float*)d_in[13];

    const size_t NH = (size_t)NN * HH;
    unsigned short* XB   = (unsigned short*)d_ws;        // x1 bf16
    unsigned short* XB2  = XB + NH;                      // x2 bf16
    unsigned short* X3B  = XB2 + NH;                     // x3 bf16
    unsigned short* AGB  = X3B + NH;                     // agg bf16
    unsigned short* WT   = AGB + NH;                     // 6 transposed bf16 weights
    float*          agg0 = (float*)(WT + 6 * 262144);
    int*            csr  = (int*)(agg0 + NN);
    int* deg       = csr;
    int* start     = csr + NN;
    int* cursor    = start + NN + 1;
    int* eidx      = cursor + NN;
    int* blockSums = eidx + EE;
    float* out = (float*)d_out;

    unsigned short* WrT2 = WT;
    unsigned short* WoT2 = WT + 1 * 262144;
    unsigned short* WrT3 = WT + 2 * 262144;
    unsigned short* WoT3 = WT + 3 * 262144;
    unsigned short* WrT4 = WT + 4 * 262144;
    unsigned short* WoT4 = WT + 5 * 262144;

    const int gGemm = 3128;  // 782 m-tiles x 4 n-tiles (128x128), XCD-chunked in-kernel

    // ---- CSR build ----
    hipMemsetAsync(deg, 0, NN * sizeof(int), stream);
    histo_deg<<<(EE + 255) / 256, 256, 0, stream>>>(dst, deg);
    scan_reduce<<<NB_SCAN, 256, 0, stream>>>(deg, blockSums);
    scan_top<<<1, 128, 0, stream>>>(blockSums, start);
    scan_down<<<NB_SCAN, 256, 0, stream>>>(deg, blockSums, start, cursor);
    csr_fill<<<(EE + 255) / 256, 256, 0, stream>>>(src, dst, cursor, eidx);

    // ---- Weights -> transposed bf16 ----
    w_transpose<<<1024, 256, 0, stream>>>(w_rel2,  WrT2);
    w_transpose<<<1024, 256, 0, stream>>>(w_root2, WoT2);
    w_transpose<<<1024, 256, 0, stream>>>(w_rel3,  WrT3);
    w_transpose<<<1024, 256, 0, stream>>>(w_root3, WoT3);
    w_transpose<<<1024, 256, 0, stream>>>(w_rel4,  WrT4);
    w_transpose<<<1024, 256, 0, stream>>>(w_root4, WoT4);

    // ---- Layer 1: x1 -> XB (bf16) ----
    gather_scalar<<<(NN + 255) / 256, 256, 0, stream>>>(x, start, eidx, agg0);
    layer1_expand<<<50000, 256, 0, stream>>>(x, agg0, w_rel1, b_rel1, w_root1, XB);

    // ---- Layer 2: x2 = relu(conv(x1)) + x1 -> XB2 (bf16) ----
    gather_rows_b<<<25000, 256, 0, stream>>>(XB, start, eidx, AGB);
    gemm_mfma<true, false><<<gGemm, 256, 0, stream>>>(
        AGB, XB, WrT2, WoT2, b_rel2, XB, nullptr, XB2);

    // ---- Layer 3: x3 = conv(x2) + x2 -> X3B (bf16) ----
    gather_rows_b<<<25000, 256, 0, stream>>>(XB2, start, eidx, AGB);
    gemm_mfma<false, false><<<gGemm, 256, 0, stream>>>(
        AGB, XB2, WrT3, WoT3, b_rel3, XB2, nullptr, X3B);

    // ---- Layer 4: x4 = conv(x3) + x3 -> d_out (f32) ----
    gather_rows_b<<<25000, 256, 0, stream>>>(X3B, start, eidx, AGB);
    gemm_mfma<false, true><<<gGemm, 256, 0, stream>>>(
        AGB, X3B, WrT4, WoT4, b_rel4, X3B, out, nullptr);
}